// Round 3
// baseline (32795.715 us; speedup 1.0000x reference)
//
#include <hip/hip_runtime.h>
#include <cmath>

#define NB 256
#define NT 256

static constexpr int B = 1024, T = 100, F = 128, H = 512;
static constexpr size_t BTF = (size_t)B * T * F;         // 13107200
static constexpr int TF = T * F;                          // 12800
static constexpr int STRB = 4 * T * F;                    // 51200 (per-b stride in inp)

// ---- workspace layout (float offsets) ----
static constexpr size_t OFF_HID   = 0;                     // B*H  (zeroed)
static constexpr size_t OFF_DEN   = 524288;                // 128  (zeroed)
static constexpr size_t OFF_LOSST = 524416;                // 128 per-t loss slots (zeroed)
static constexpr size_t OFF_BAR   = 524544;                // 2 unsigned (zeroed)
static constexpr size_t ZERO_FLOATS = 524552;
static constexpr size_t OFF_H    = 524552;                 // B*H
static constexpr size_t OFF_GH   = OFF_H + (size_t)B * H;          // B*3H
static constexpr size_t OFF_XHAT = OFF_GH + (size_t)B * 3 * H;     // B*F
static constexpr size_t OFF_GX   = OFF_XHAT + (size_t)B * F;
static constexpr size_t OFF_CONC = OFF_GX + (size_t)B * F;
static constexpr size_t OFF_BETA = OFF_CONC + (size_t)B * F;
static constexpr size_t OFF_CC   = OFF_BETA + (size_t)B * F;

__device__ __forceinline__ float4 ld4(const float* p) {
    return *reinterpret_cast<const float4*>(p);
}
__device__ __forceinline__ float sigm(float x) { return 1.f / (1.f + expf(-x)); }

// grid barrier: sense via monotonically increasing release counter
__device__ __forceinline__ void gsync(unsigned* bar) {
    __syncthreads();
    __threadfence();
    if (threadIdx.x == 0) {
        unsigned* arrive  = bar;
        unsigned* release = bar + 1;
        unsigned gen = __hip_atomic_load(release, __ATOMIC_RELAXED, __HIP_MEMORY_SCOPE_AGENT);
        unsigned prev = __hip_atomic_fetch_add(arrive, 1u, __ATOMIC_ACQ_REL, __HIP_MEMORY_SCOPE_AGENT);
        if (prev == NB - 1) {
            __hip_atomic_store(arrive, 0u, __ATOMIC_RELAXED, __HIP_MEMORY_SCOPE_AGENT);
            __hip_atomic_fetch_add(release, 1u, __ATOMIC_ACQ_REL, __HIP_MEMORY_SCOPE_AGENT);
        } else {
            while (__hip_atomic_load(release, __ATOMIC_RELAXED, __HIP_MEMORY_SCOPE_AGENT) == gen) {
                __builtin_amdgcn_s_sleep(2);
            }
        }
        __threadfence();
    }
    __syncthreads();
}

__device__ __forceinline__ void stage8(float* __restrict__ dst, int kq, int sr,
                                       float4 p0, float4 p1) {
    dst[(kq + 0) * 64 + sr] = p0.x; dst[(kq + 1) * 64 + sr] = p0.y;
    dst[(kq + 2) * 64 + sr] = p0.z; dst[(kq + 3) * 64 + sr] = p0.w;
    dst[(kq + 4) * 64 + sr] = p1.x; dst[(kq + 5) * 64 + sr] = p1.y;
    dst[(kq + 6) * 64 + sr] = p1.z; dst[(kq + 7) * 64 + sr] = p1.w;
}

// C_tile[64x64] = A[64xK] * B[64xK]^T ; loaders return float4 over 4 consecutive k.
// Double-buffered LDS (sAB = 2 bufs x (A 32x64 + B 32x64)), 1 sync per 32-k chunk,
// next chunk prefetched into registers during compute (1 wave/SIMD -> ILP-only hiding).
template <typename FA, typename FB>
__device__ __forceinline__ void gemm_tile64(int K, FA loadA4, FB loadB4,
                                            float* __restrict__ sAB, float acc[4][4]) {
    const int tid = threadIdx.x;
    const int sr = tid & 63;           // staging row (A row / B col)
    const int kq = (tid >> 6) << 3;    // 0,8,16,24 : k-rows staged by this wave
    const int tx = tid & 15, ty = tid >> 4;
    const int nc = K >> 5;

    float4 pa0 = loadA4(sr, kq);
    float4 pa1 = loadA4(sr, kq + 4);
    float4 pb0 = loadB4(sr, kq);
    float4 pb1 = loadB4(sr, kq + 4);
    stage8(sAB, kq, sr, pa0, pa1);
    stage8(sAB + 2048, kq, sr, pb0, pb1);
    __syncthreads();

    for (int c = 0; c < nc; ++c) {
        const float* sA = sAB + (c & 1) * 4096;
        const float* sB = sA + 2048;
        if (c + 1 < nc) {
            const int k0 = (c + 1) << 5;
            pa0 = loadA4(sr, k0 + kq);
            pa1 = loadA4(sr, k0 + kq + 4);
            pb0 = loadB4(sr, k0 + kq);
            pb1 = loadB4(sr, k0 + kq + 4);
        }
#pragma unroll
        for (int kk = 0; kk < 32; ++kk) {
            const float4 av = *reinterpret_cast<const float4*>(&sA[kk * 64 + ty * 4]);
            const float4 bv = *reinterpret_cast<const float4*>(&sB[kk * 64 + tx * 4]);
            const float a0[4] = {av.x, av.y, av.z, av.w};
            const float b0[4] = {bv.x, bv.y, bv.z, bv.w};
#pragma unroll
            for (int i = 0; i < 4; ++i)
#pragma unroll
                for (int j = 0; j < 4; ++j)
                    acc[i][j] = fmaf(a0[i], b0[j], acc[i][j]);
        }
        if (c + 1 < nc) {
            float* dA = sAB + ((c + 1) & 1) * 4096;
            stage8(dA, kq, sr, pa0, pa1);
            stage8(dA + 2048, kq, sr, pb0, pb1);
        }
        __syncthreads();
    }
}

__global__ void __launch_bounds__(NT) mgru_main(
    const float* __restrict__ inp,
    const float* __restrict__ W_dh, const float* __restrict__ b_dh,
    const float* __restrict__ w_dx, const float* __restrict__ b_dx,
    const float* __restrict__ W_out, const float* __restrict__ b_out,
    const float* __restrict__ W_z,   const float* __restrict__ b_z,
    const float* __restrict__ W_cat, const float* __restrict__ b_cat,
    const float* __restrict__ W_beta,const float* __restrict__ b_beta,
    const float* __restrict__ W_ih,  const float* __restrict__ b_ih,
    const float* __restrict__ W_hh,  const float* __restrict__ b_hh,
    float* __restrict__ out, float* __restrict__ ws)
{
    __shared__ float sAB[2 * 4096];   // 32 KiB: 2 bufs x (A 32x64 + B 32x64)

    float* hid   = ws + OFF_HID;
    float* den   = ws + OFF_DEN;
    float* lossT = ws + OFF_LOSST;
    unsigned* bar = reinterpret_cast<unsigned*>(ws + OFF_BAR);
    float* hdec  = ws + OFF_H;
    float* gh    = ws + OFF_GH;
    float* xhat  = ws + OFF_XHAT;
    float* gx    = ws + OFF_GX;
    float* conc  = ws + OFF_CONC;
    float* betav = ws + OFF_BETA;
    float* ccw   = ws + OFF_CC;

    const int bid = blockIdx.x, tid = threadIdx.x;
    const int tx = tid & 15, ty = tid >> 4;

    // ---- prologue: den[t] = sum_b,f masks[b,t,f] ----
    for (int s = bid * NT + tid; s < B * T; s += NB * NT) {
        int b = s / T, t = s - b * T;
        const float* mrow = inp + (size_t)b * STRB + 2 * TF + (size_t)t * F;
        float sum = 0.f;
        for (int f = 0; f < F; f += 4) {
            float4 m4 = ld4(mrow + f);
            sum += m4.x + m4.y + m4.z + m4.w;
        }
        atomicAdd(&den[t], sum);
    }
    gsync(bar);

    for (int t = 0; t < T; ++t) {
        const size_t tF = (size_t)t * F;
        // ================= Phase 1 =================
        if (bid < 128) {  // gamma_h & hdec : [1024,512], K=128
            const int rt = bid >> 3, ct = bid & 7;
            float acc[4][4] = {};
            gemm_tile64(128,
                [=](int r, int k) { return ld4(inp + (size_t)(rt * 64 + r) * STRB + TF + tF + k); },
                [=](int c, int k) { return ld4(W_dh + (size_t)(ct * 64 + c) * F + k); },
                sAB, acc);
#pragma unroll
            for (int i = 0; i < 4; ++i) {
                int b = rt * 64 + ty * 4 + i;
#pragma unroll
                for (int j = 0; j < 4; ++j) {
                    int c = ct * 64 + tx * 4 + j;
                    float g = expf(-fmaxf(acc[i][j] + b_dh[c], 0.f));
                    hdec[(size_t)b * H + c] = hid[(size_t)b * H + c] * g;
                }
            }
        } else if (bid < 160) {  // x_hat : [1024,128], K=512
            const int t2 = bid - 128, rt = t2 >> 1, ct = t2 & 1;
            float acc[4][4] = {};
            gemm_tile64(512,
                [=](int r, int k) { return ld4(hid + (size_t)(rt * 64 + r) * H + k); },
                [=](int c, int k) { return ld4(W_out + (size_t)(ct * 64 + c) * H + k); },
                sAB, acc);
#pragma unroll
            for (int i = 0; i < 4; ++i) {
                int b = rt * 64 + ty * 4 + i;
#pragma unroll
                for (int j = 0; j < 4; ++j) {
                    int c = ct * 64 + tx * 4 + j;
                    xhat[(size_t)b * F + c] = acc[i][j] + b_out[c];
                }
            }
        } else if (bid < 224) {  // gamma_x elementwise
            const int eb = bid - 160;
            const int base = eb * 2048 + tid * 8;
#pragma unroll
            for (int s = 0; s < 2; ++s) {
                int idx = base + s * 4;
                int b = idx >> 7, f = idx & 127;
                float4 d4 = ld4(inp + (size_t)b * STRB + TF + tF + f);
                float4 w4 = ld4(w_dx + f), c4 = ld4(b_dx + f);
                float4 q;
                q.x = expf(-fmaxf(d4.x * w4.x + c4.x, 0.f));
                q.y = expf(-fmaxf(d4.y * w4.y + c4.y, 0.f));
                q.z = expf(-fmaxf(d4.z * w4.z + c4.z, 0.f));
                q.w = expf(-fmaxf(d4.w * w4.w + c4.w, 0.f));
                *reinterpret_cast<float4*>(&gx[idx]) = q;
            }
        }
        gsync(bar);
        // ================= Phase 2 =================
        for (int item = bid; item < 448; item += NB) {
            if (item < 384) {  // gh : [1024,1536], K=512
                const int rt = item / 24, ct = item % 24;
                float acc[4][4] = {};
                gemm_tile64(512,
                    [=](int r, int k) { return ld4(hdec + (size_t)(rt * 64 + r) * H + k); },
                    [=](int c, int k) { return ld4(W_hh + (size_t)(ct * 64 + c) * H + k); },
                    sAB, acc);
#pragma unroll
                for (int i = 0; i < 4; ++i) {
                    int b = rt * 64 + ty * 4 + i;
#pragma unroll
                    for (int j = 0; j < 4; ++j) {
                        int c = ct * 64 + tx * 4 + j;
                        gh[(size_t)b * 1536 + c] = acc[i][j] + b_hh[c];
                    }
                }
            } else if (item < 416) {  // concat_hat : [1024,128], K=256
                const int t2 = item - 384, rt = t2 >> 1, ct = t2 & 1;
                float acc[4][4] = {};
                gemm_tile64(256,
                    [=](int r, int k) {
                        int b = rt * 64 + r;
                        if (k < 128) {
                            float4 v4 = ld4(inp + (size_t)b * STRB + tF + k);
                            float4 m4 = ld4(inp + (size_t)b * STRB + 2 * TF + tF + k);
                            float4 x4 = ld4(xhat + (size_t)b * F + k);
                            float4 q;
                            q.x = m4.x * v4.x + (1.f - m4.x) * x4.x;
                            q.y = m4.y * v4.y + (1.f - m4.y) * x4.y;
                            q.z = m4.z * v4.z + (1.f - m4.z) * x4.z;
                            q.w = m4.w * v4.w + (1.f - m4.w) * x4.w;
                            return q;
                        }
                        return ld4(inp + (size_t)b * STRB + 3 * TF + tF + (k - 128));
                    },
                    [=](int c, int k) { return ld4(W_cat + (size_t)(ct * 64 + c) * (2 * F) + k); },
                    sAB, acc);
#pragma unroll
                for (int i = 0; i < 4; ++i) {
                    int b = rt * 64 + ty * 4 + i;
#pragma unroll
                    for (int j = 0; j < 4; ++j) {
                        int c = ct * 64 + tx * 4 + j;
                        conc[(size_t)b * F + c] = acc[i][j] + b_cat[c];
                    }
                }
            } else {  // beta : [1024,128], K=256
                const int t2 = item - 416, rt = t2 >> 1, ct = t2 & 1;
                float acc[4][4] = {};
                gemm_tile64(256,
                    [=](int r, int k) {
                        int b = rt * 64 + r;
                        if (k < 128) return ld4(gx + (size_t)b * F + k);
                        return ld4(inp + (size_t)b * STRB + 2 * TF + tF + (k - 128));
                    },
                    [=](int c, int k) { return ld4(W_beta + (size_t)(ct * 64 + c) * (2 * F) + k); },
                    sAB, acc);
#pragma unroll
                for (int i = 0; i < 4; ++i) {
                    int b = rt * 64 + ty * 4 + i;
#pragma unroll
                    for (int j = 0; j < 4; ++j) {
                        int c = ct * 64 + tx * 4 + j;
                        betav[(size_t)b * F + c] = sigm(acc[i][j] + b_beta[c]);
                    }
                }
            }
        }
        gsync(bar);
        // ================= Phase 3 =================
        if (bid < 32) {  // z_hat + elementwise + outputs + loss
            const int rt = bid >> 1, ct = bid & 1;
            float acc[4][4] = {};
            gemm_tile64(128,
                [=](int r, int k) {
                    int b = rt * 64 + r;
                    float4 v4 = ld4(inp + (size_t)b * STRB + tF + k);
                    float4 m4 = ld4(inp + (size_t)b * STRB + 2 * TF + tF + k);
                    float4 c4 = ld4(conc + (size_t)b * F + k);
                    float4 q;
                    q.x = m4.x * v4.x + (1.f - m4.x) * c4.x;
                    q.y = m4.y * v4.y + (1.f - m4.y) * c4.y;
                    q.z = m4.z * v4.z + (1.f - m4.z) * c4.z;
                    q.w = m4.w * v4.w + (1.f - m4.w) * c4.w;
                    return q;
                },
                [=](int c, int k) {
                    float4 w = ld4(W_z + (size_t)(ct * 64 + c) * F + k);
                    int cg = ct * 64 + c;  // zero diagonal of W_z
                    w.x = (cg == k + 0) ? 0.f : w.x;
                    w.y = (cg == k + 1) ? 0.f : w.y;
                    w.z = (cg == k + 2) ? 0.f : w.z;
                    w.w = (cg == k + 3) ? 0.f : w.w;
                    return w;
                },
                sAB, acc);
            float lsum = 0.f;
#pragma unroll
            for (int i = 0; i < 4; ++i) {
                int b = rt * 64 + ty * 4 + i;
#pragma unroll
                for (int j = 0; j < 4; ++j) {
                    int c = ct * 64 + tx * 4 + j;
                    float zh = acc[i][j] + b_z[c];
                    float xh = xhat[(size_t)b * F + c];
                    float bt = betav[(size_t)b * F + c];
                    float ch = bt * zh + (1.f - bt) * xh;
                    const size_t ib = (size_t)b * STRB + tF;
                    float v = inp[ib + c];
                    float m = inp[ib + 2 * TF + c];
                    float cc = m * v + (1.f - m) * ch;
                    out[(size_t)b * TF + tF + c] = ch;
                    out[BTF + (size_t)b * TF + tF + c] = cc;
                    ccw[(size_t)b * F + c] = cc;
                    float co = conc[(size_t)b * F + c];
                    lsum += m * (2.f * fabsf(v - xh) + fabsf(v - co) +
                                 fabsf(v - zh) + fabsf(v - ch));
                }
            }
            __syncthreads();
            sAB[tid] = lsum;
            __syncthreads();
            for (int s = 128; s > 0; s >>= 1) {
                if (tid < s) sAB[tid] += sAB[tid + s];
                __syncthreads();
            }
            if (tid == 0) atomicAdd(&lossT[t], sAB[0] / (den[t] + 1e-5f));
        }
        gsync(bar);
        // ================= Phase 4 =================
        if (bid < 128) {  // gi (3 gates) + h_new : rows rt*64, h-cols hc*64
            const int rt = bid >> 3, hc = bid & 7;
            float acc3[3][4][4] = {};
#pragma unroll
            for (int g = 0; g < 3; ++g) {
                gemm_tile64(256,
                    [=](int r, int k) {
                        int b = rt * 64 + r;
                        if (k < 128) return ld4(ccw + (size_t)b * F + k);
                        return ld4(inp + (size_t)b * STRB + 2 * TF + tF + (k - 128));
                    },
                    [=](int c, int k) { return ld4(W_ih + (size_t)(g * H + hc * 64 + c) * (2 * F) + k); },
                    sAB, acc3[g]);
            }
#pragma unroll
            for (int i = 0; i < 4; ++i) {
                int b = rt * 64 + ty * 4 + i;
#pragma unroll
                for (int j = 0; j < 4; ++j) {
                    int c = hc * 64 + tx * 4 + j;
                    float ir  = acc3[0][i][j] + b_ih[c];
                    float iz  = acc3[1][i][j] + b_ih[H + c];
                    float inn = acc3[2][i][j] + b_ih[2 * H + c];
                    float hr = gh[(size_t)b * 1536 + c];
                    float hz = gh[(size_t)b * 1536 + H + c];
                    float hn = gh[(size_t)b * 1536 + 2 * H + c];
                    float hv = hdec[(size_t)b * H + c];
                    float rg = sigm(ir + hr);
                    float zg = sigm(iz + hz);
                    float ng = tanhf(inn + rg * hn);
                    hid[(size_t)b * H + c] = (1.f - zg) * ng + zg * hv;
                }
            }
        }
        gsync(bar);
    }
    if (bid == 0 && tid == 0) {
        float s = 0.f;
        for (int t = 0; t < T; ++t) s += lossT[t];
        out[2 * BTF] = s * 5.0f;
    }
}

extern "C" void kernel_launch(void* const* d_in, const int* in_sizes, int n_in,
                              void* d_out, int out_size, void* d_ws, size_t ws_size,
                              hipStream_t stream) {
    const float* inp    = (const float*)d_in[0];
    const float* W_dh   = (const float*)d_in[1];
    const float* b_dh   = (const float*)d_in[2];
    const float* w_dx   = (const float*)d_in[3];
    const float* b_dx   = (const float*)d_in[4];
    const float* W_out  = (const float*)d_in[5];
    const float* b_out  = (const float*)d_in[6];
    const float* W_z    = (const float*)d_in[7];
    const float* b_z    = (const float*)d_in[8];
    const float* W_cat  = (const float*)d_in[9];
    const float* b_cat  = (const float*)d_in[10];
    const float* W_beta = (const float*)d_in[11];
    const float* b_beta = (const float*)d_in[12];
    const float* W_ih   = (const float*)d_in[13];
    const float* b_ih   = (const float*)d_in[14];
    const float* W_hh   = (const float*)d_in[15];
    const float* b_hh   = (const float*)d_in[16];

    // zero hid / den / per-t loss / barrier counters (ws is poisoned 0xAA each launch)
    hipMemsetAsync(d_ws, 0, ZERO_FLOATS * sizeof(float), stream);

    mgru_main<<<NB, NT, 0, stream>>>(inp, W_dh, b_dh, w_dx, b_dx, W_out, b_out,
                                     W_z, b_z, W_cat, b_cat, W_beta, b_beta,
                                     W_ih, b_ih, W_hh, b_hh,
                                     (float*)d_out, (float*)d_ws);
}

// Round 4
// 32772.342 us; speedup vs baseline: 1.0007x; 1.0007x over previous
//
#include <hip/hip_runtime.h>
#include <cmath>

#define NB 256
#define NT 256

static constexpr int B = 1024, T = 100, F = 128, H = 512;
static constexpr size_t BTF = (size_t)B * T * F;         // 13107200
static constexpr int TF = T * F;                          // 12800
static constexpr int STRB = 4 * T * F;                    // 51200 (per-b stride in inp)

// ---- workspace layout (float offsets) ----
static constexpr size_t OFF_HID   = 0;                     // B*H  (zeroed)
static constexpr size_t OFF_DEN   = 524288;                // 128  (zeroed)
static constexpr size_t OFF_LOSST = 524416;                // 128 per-t loss slots (zeroed)
static constexpr size_t OFF_BAR   = 524544;                // 2 unsigned (zeroed)
static constexpr size_t ZERO_FLOATS = 524552;
static constexpr size_t OFF_H    = 524552;                 // B*H
static constexpr size_t OFF_GH   = OFF_H + (size_t)B * H;          // B*3H
static constexpr size_t OFF_XHAT = OFF_GH + (size_t)B * 3 * H;     // B*F
static constexpr size_t OFF_GX   = OFF_XHAT + (size_t)B * F;
static constexpr size_t OFF_CONC = OFF_GX + (size_t)B * F;
static constexpr size_t OFF_BETA = OFF_CONC + (size_t)B * F;
static constexpr size_t OFF_CC   = OFF_BETA + (size_t)B * F;

__device__ __forceinline__ float4 ld4(const float* p) {
    return *reinterpret_cast<const float4*>(p);
}
__device__ __forceinline__ float sigm(float x) { return 1.f / (1.f + expf(-x)); }

// grid barrier: sense via monotonically increasing release counter
__device__ __forceinline__ void gsync(unsigned* bar) {
    __syncthreads();
    __threadfence();
    if (threadIdx.x == 0) {
        unsigned* arrive  = bar;
        unsigned* release = bar + 1;
        unsigned gen = __hip_atomic_load(release, __ATOMIC_RELAXED, __HIP_MEMORY_SCOPE_AGENT);
        unsigned prev = __hip_atomic_fetch_add(arrive, 1u, __ATOMIC_ACQ_REL, __HIP_MEMORY_SCOPE_AGENT);
        if (prev == NB - 1) {
            __hip_atomic_store(arrive, 0u, __ATOMIC_RELAXED, __HIP_MEMORY_SCOPE_AGENT);
            __hip_atomic_fetch_add(release, 1u, __ATOMIC_ACQ_REL, __HIP_MEMORY_SCOPE_AGENT);
        } else {
            while (__hip_atomic_load(release, __ATOMIC_RELAXED, __HIP_MEMORY_SCOPE_AGENT) == gen) {
                __builtin_amdgcn_s_sleep(2);
            }
        }
        __threadfence();
    }
    __syncthreads();
}

// write one float4 (4 consecutive k, one row) into k-major LDS tile [32][64]
__device__ __forceinline__ void stage4(float* __restrict__ dst, int k, int r, float4 p) {
    dst[(k + 0) * 64 + r] = p.x; dst[(k + 1) * 64 + r] = p.y;
    dst[(k + 2) * 64 + r] = p.z; dst[(k + 3) * 64 + r] = p.w;
}

// C_tile[64x64] = A[64xK] * B[64xK]^T ; loaders return float4 over 4 consecutive k.
// COALESCED staging: thread loads row lr = tid>>2, k = (tid&3)*4 and +16 -> each
// 4-lane cluster reads one contiguous 64B line (16 transactions/instr, 100% util).
// Double-buffered LDS (2 bufs x (A 32x64 + B 32x64)), 1 sync per 32-k chunk,
// next chunk prefetched into registers during compute (1 wave/SIMD -> ILP hiding).
template <typename FA, typename FB>
__device__ __forceinline__ void gemm_tile64(int K, FA loadA4, FB loadB4,
                                            float* __restrict__ sAB, float acc[4][4]) {
    const int tid = threadIdx.x;
    const int lr = tid >> 2;            // 0..63 : row (A) / col (B) staged by this thread
    const int lk = (tid & 3) << 2;      // 0,4,8,12 : first k of this thread's float4
    const int tx = tid & 15, ty = tid >> 4;
    const int nc = K >> 5;

    float4 pa0 = loadA4(lr, lk);
    float4 pa1 = loadA4(lr, lk + 16);
    float4 pb0 = loadB4(lr, lk);
    float4 pb1 = loadB4(lr, lk + 16);
    stage4(sAB, lk, lr, pa0);
    stage4(sAB, lk + 16, lr, pa1);
    stage4(sAB + 2048, lk, lr, pb0);
    stage4(sAB + 2048, lk + 16, lr, pb1);
    __syncthreads();

    for (int c = 0; c < nc; ++c) {
        const float* sA = sAB + (c & 1) * 4096;
        const float* sB = sA + 2048;
        if (c + 1 < nc) {
            const int k0 = (c + 1) << 5;
            pa0 = loadA4(lr, k0 + lk);
            pa1 = loadA4(lr, k0 + lk + 16);
            pb0 = loadB4(lr, k0 + lk);
            pb1 = loadB4(lr, k0 + lk + 16);
        }
#pragma unroll
        for (int kk = 0; kk < 32; ++kk) {
            const float4 av = *reinterpret_cast<const float4*>(&sA[kk * 64 + ty * 4]);
            const float4 bv = *reinterpret_cast<const float4*>(&sB[kk * 64 + tx * 4]);
            const float a0[4] = {av.x, av.y, av.z, av.w};
            const float b0[4] = {bv.x, bv.y, bv.z, bv.w};
#pragma unroll
            for (int i = 0; i < 4; ++i)
#pragma unroll
                for (int j = 0; j < 4; ++j)
                    acc[i][j] = fmaf(a0[i], b0[j], acc[i][j]);
        }
        if (c + 1 < nc) {
            float* dA = sAB + ((c + 1) & 1) * 4096;
            stage4(dA, lk, lr, pa0);
            stage4(dA, lk + 16, lr, pa1);
            stage4(dA + 2048, lk, lr, pb0);
            stage4(dA + 2048, lk + 16, lr, pb1);
        }
        __syncthreads();
    }
}

__global__ void __launch_bounds__(NT) mgru_main(
    const float* __restrict__ inp,
    const float* __restrict__ W_dh, const float* __restrict__ b_dh,
    const float* __restrict__ w_dx, const float* __restrict__ b_dx,
    const float* __restrict__ W_out, const float* __restrict__ b_out,
    const float* __restrict__ W_z,   const float* __restrict__ b_z,
    const float* __restrict__ W_cat, const float* __restrict__ b_cat,
    const float* __restrict__ W_beta,const float* __restrict__ b_beta,
    const float* __restrict__ W_ih,  const float* __restrict__ b_ih,
    const float* __restrict__ W_hh,  const float* __restrict__ b_hh,
    float* __restrict__ out, float* __restrict__ ws)
{
    __shared__ float sAB[2 * 4096];   // 32 KiB: 2 bufs x (A 32x64 + B 32x64)

    float* hid   = ws + OFF_HID;
    float* den   = ws + OFF_DEN;
    float* lossT = ws + OFF_LOSST;
    unsigned* bar = reinterpret_cast<unsigned*>(ws + OFF_BAR);
    float* hdec  = ws + OFF_H;
    float* gh    = ws + OFF_GH;
    float* xhat  = ws + OFF_XHAT;
    float* gx    = ws + OFF_GX;
    float* conc  = ws + OFF_CONC;
    float* betav = ws + OFF_BETA;
    float* ccw   = ws + OFF_CC;

    const int bid = blockIdx.x, tid = threadIdx.x;
    const int tx = tid & 15, ty = tid >> 4;

    // ---- prologue: den[t] = sum_b,f masks[b,t,f] ----
    for (int s = bid * NT + tid; s < B * T; s += NB * NT) {
        int b = s / T, t = s - b * T;
        const float* mrow = inp + (size_t)b * STRB + 2 * TF + (size_t)t * F;
        float sum = 0.f;
        for (int f = 0; f < F; f += 4) {
            float4 m4 = ld4(mrow + f);
            sum += m4.x + m4.y + m4.z + m4.w;
        }
        atomicAdd(&den[t], sum);
    }
    gsync(bar);

    for (int t = 0; t < T; ++t) {
        const size_t tF = (size_t)t * F;
        // ================= Phase 1 =================
        if (bid < 128) {  // gamma_h & hdec : [1024,512], K=128
            const int rt = bid >> 3, ct = bid & 7;
            float acc[4][4] = {};
            gemm_tile64(128,
                [=](int r, int k) { return ld4(inp + (size_t)(rt * 64 + r) * STRB + TF + tF + k); },
                [=](int c, int k) { return ld4(W_dh + (size_t)(ct * 64 + c) * F + k); },
                sAB, acc);
#pragma unroll
            for (int i = 0; i < 4; ++i) {
                int b = rt * 64 + ty * 4 + i;
#pragma unroll
                for (int j = 0; j < 4; ++j) {
                    int c = ct * 64 + tx * 4 + j;
                    float g = expf(-fmaxf(acc[i][j] + b_dh[c], 0.f));
                    hdec[(size_t)b * H + c] = hid[(size_t)b * H + c] * g;
                }
            }
        } else if (bid < 160) {  // x_hat : [1024,128], K=512
            const int t2 = bid - 128, rt = t2 >> 1, ct = t2 & 1;
            float acc[4][4] = {};
            gemm_tile64(512,
                [=](int r, int k) { return ld4(hid + (size_t)(rt * 64 + r) * H + k); },
                [=](int c, int k) { return ld4(W_out + (size_t)(ct * 64 + c) * H + k); },
                sAB, acc);
#pragma unroll
            for (int i = 0; i < 4; ++i) {
                int b = rt * 64 + ty * 4 + i;
#pragma unroll
                for (int j = 0; j < 4; ++j) {
                    int c = ct * 64 + tx * 4 + j;
                    xhat[(size_t)b * F + c] = acc[i][j] + b_out[c];
                }
            }
        } else if (bid < 224) {  // gamma_x elementwise
            const int eb = bid - 160;
            const int base = eb * 2048 + tid * 8;
#pragma unroll
            for (int s = 0; s < 2; ++s) {
                int idx = base + s * 4;
                int b = idx >> 7, f = idx & 127;
                float4 d4 = ld4(inp + (size_t)b * STRB + TF + tF + f);
                float4 w4 = ld4(w_dx + f), c4 = ld4(b_dx + f);
                float4 q;
                q.x = expf(-fmaxf(d4.x * w4.x + c4.x, 0.f));
                q.y = expf(-fmaxf(d4.y * w4.y + c4.y, 0.f));
                q.z = expf(-fmaxf(d4.z * w4.z + c4.z, 0.f));
                q.w = expf(-fmaxf(d4.w * w4.w + c4.w, 0.f));
                *reinterpret_cast<float4*>(&gx[idx]) = q;
            }
        }
        gsync(bar);
        // ================= Phase 2 =================
        for (int item = bid; item < 448; item += NB) {
            if (item < 384) {  // gh : [1024,1536], K=512
                const int rt = item / 24, ct = item % 24;
                float acc[4][4] = {};
                gemm_tile64(512,
                    [=](int r, int k) { return ld4(hdec + (size_t)(rt * 64 + r) * H + k); },
                    [=](int c, int k) { return ld4(W_hh + (size_t)(ct * 64 + c) * H + k); },
                    sAB, acc);
#pragma unroll
                for (int i = 0; i < 4; ++i) {
                    int b = rt * 64 + ty * 4 + i;
#pragma unroll
                    for (int j = 0; j < 4; ++j) {
                        int c = ct * 64 + tx * 4 + j;
                        gh[(size_t)b * 1536 + c] = acc[i][j] + b_hh[c];
                    }
                }
            } else if (item < 416) {  // concat_hat : [1024,128], K=256
                const int t2 = item - 384, rt = t2 >> 1, ct = t2 & 1;
                float acc[4][4] = {};
                gemm_tile64(256,
                    [=](int r, int k) {
                        int b = rt * 64 + r;
                        if (k < 128) {
                            float4 v4 = ld4(inp + (size_t)b * STRB + tF + k);
                            float4 m4 = ld4(inp + (size_t)b * STRB + 2 * TF + tF + k);
                            float4 x4 = ld4(xhat + (size_t)b * F + k);
                            float4 q;
                            q.x = m4.x * v4.x + (1.f - m4.x) * x4.x;
                            q.y = m4.y * v4.y + (1.f - m4.y) * x4.y;
                            q.z = m4.z * v4.z + (1.f - m4.z) * x4.z;
                            q.w = m4.w * v4.w + (1.f - m4.w) * x4.w;
                            return q;
                        }
                        return ld4(inp + (size_t)b * STRB + 3 * TF + tF + (k - 128));
                    },
                    [=](int c, int k) { return ld4(W_cat + (size_t)(ct * 64 + c) * (2 * F) + k); },
                    sAB, acc);
#pragma unroll
                for (int i = 0; i < 4; ++i) {
                    int b = rt * 64 + ty * 4 + i;
#pragma unroll
                    for (int j = 0; j < 4; ++j) {
                        int c = ct * 64 + tx * 4 + j;
                        conc[(size_t)b * F + c] = acc[i][j] + b_cat[c];
                    }
                }
            } else {  // beta : [1024,128], K=256
                const int t2 = item - 416, rt = t2 >> 1, ct = t2 & 1;
                float acc[4][4] = {};
                gemm_tile64(256,
                    [=](int r, int k) {
                        int b = rt * 64 + r;
                        if (k < 128) return ld4(gx + (size_t)b * F + k);
                        return ld4(inp + (size_t)b * STRB + 2 * TF + tF + (k - 128));
                    },
                    [=](int c, int k) { return ld4(W_beta + (size_t)(ct * 64 + c) * (2 * F) + k); },
                    sAB, acc);
#pragma unroll
                for (int i = 0; i < 4; ++i) {
                    int b = rt * 64 + ty * 4 + i;
#pragma unroll
                    for (int j = 0; j < 4; ++j) {
                        int c = ct * 64 + tx * 4 + j;
                        betav[(size_t)b * F + c] = sigm(acc[i][j] + b_beta[c]);
                    }
                }
            }
        }
        gsync(bar);
        // ================= Phase 3 =================
        if (bid < 32) {  // z_hat + elementwise + outputs + loss
            const int rt = bid >> 1, ct = bid & 1;
            float acc[4][4] = {};
            gemm_tile64(128,
                [=](int r, int k) {
                    int b = rt * 64 + r;
                    float4 v4 = ld4(inp + (size_t)b * STRB + tF + k);
                    float4 m4 = ld4(inp + (size_t)b * STRB + 2 * TF + tF + k);
                    float4 c4 = ld4(conc + (size_t)b * F + k);
                    float4 q;
                    q.x = m4.x * v4.x + (1.f - m4.x) * c4.x;
                    q.y = m4.y * v4.y + (1.f - m4.y) * c4.y;
                    q.z = m4.z * v4.z + (1.f - m4.z) * c4.z;
                    q.w = m4.w * v4.w + (1.f - m4.w) * c4.w;
                    return q;
                },
                [=](int c, int k) {
                    float4 w = ld4(W_z + (size_t)(ct * 64 + c) * F + k);
                    int cg = ct * 64 + c;  // zero diagonal of W_z
                    w.x = (cg == k + 0) ? 0.f : w.x;
                    w.y = (cg == k + 1) ? 0.f : w.y;
                    w.z = (cg == k + 2) ? 0.f : w.z;
                    w.w = (cg == k + 3) ? 0.f : w.w;
                    return w;
                },
                sAB, acc);
            float lsum = 0.f;
#pragma unroll
            for (int i = 0; i < 4; ++i) {
                int b = rt * 64 + ty * 4 + i;
#pragma unroll
                for (int j = 0; j < 4; ++j) {
                    int c = ct * 64 + tx * 4 + j;
                    float zh = acc[i][j] + b_z[c];
                    float xh = xhat[(size_t)b * F + c];
                    float bt = betav[(size_t)b * F + c];
                    float ch = bt * zh + (1.f - bt) * xh;
                    const size_t ib = (size_t)b * STRB + tF;
                    float v = inp[ib + c];
                    float m = inp[ib + 2 * TF + c];
                    float cc = m * v + (1.f - m) * ch;
                    out[(size_t)b * TF + tF + c] = ch;
                    out[BTF + (size_t)b * TF + tF + c] = cc;
                    ccw[(size_t)b * F + c] = cc;
                    float co = conc[(size_t)b * F + c];
                    lsum += m * (2.f * fabsf(v - xh) + fabsf(v - co) +
                                 fabsf(v - zh) + fabsf(v - ch));
                }
            }
            __syncthreads();
            sAB[tid] = lsum;
            __syncthreads();
            for (int s = 128; s > 0; s >>= 1) {
                if (tid < s) sAB[tid] += sAB[tid + s];
                __syncthreads();
            }
            if (tid == 0) atomicAdd(&lossT[t], sAB[0] / (den[t] + 1e-5f));
        }
        gsync(bar);
        // ================= Phase 4 =================
        if (bid < 128) {  // gi (3 gates) + h_new : rows rt*64, h-cols hc*64
            const int rt = bid >> 3, hc = bid & 7;
            float acc3[3][4][4] = {};
#pragma unroll
            for (int g = 0; g < 3; ++g) {
                gemm_tile64(256,
                    [=](int r, int k) {
                        int b = rt * 64 + r;
                        if (k < 128) return ld4(ccw + (size_t)b * F + k);
                        return ld4(inp + (size_t)b * STRB + 2 * TF + tF + (k - 128));
                    },
                    [=](int c, int k) { return ld4(W_ih + (size_t)(g * H + hc * 64 + c) * (2 * F) + k); },
                    sAB, acc3[g]);
            }
#pragma unroll
            for (int i = 0; i < 4; ++i) {
                int b = rt * 64 + ty * 4 + i;
#pragma unroll
                for (int j = 0; j < 4; ++j) {
                    int c = hc * 64 + tx * 4 + j;
                    float ir  = acc3[0][i][j] + b_ih[c];
                    float iz  = acc3[1][i][j] + b_ih[H + c];
                    float inn = acc3[2][i][j] + b_ih[2 * H + c];
                    float hr = gh[(size_t)b * 1536 + c];
                    float hz = gh[(size_t)b * 1536 + H + c];
                    float hn = gh[(size_t)b * 1536 + 2 * H + c];
                    float hv = hdec[(size_t)b * H + c];
                    float rg = sigm(ir + hr);
                    float zg = sigm(iz + hz);
                    float ng = tanhf(inn + rg * hn);
                    hid[(size_t)b * H + c] = (1.f - zg) * ng + zg * hv;
                }
            }
        }
        gsync(bar);
    }
    if (bid == 0 && tid == 0) {
        float s = 0.f;
        for (int t = 0; t < T; ++t) s += lossT[t];
        out[2 * BTF] = s * 5.0f;
    }
}

extern "C" void kernel_launch(void* const* d_in, const int* in_sizes, int n_in,
                              void* d_out, int out_size, void* d_ws, size_t ws_size,
                              hipStream_t stream) {
    const float* inp    = (const float*)d_in[0];
    const float* W_dh   = (const float*)d_in[1];
    const float* b_dh   = (const float*)d_in[2];
    const float* w_dx   = (const float*)d_in[3];
    const float* b_dx   = (const float*)d_in[4];
    const float* W_out  = (const float*)d_in[5];
    const float* b_out  = (const float*)d_in[6];
    const float* W_z    = (const float*)d_in[7];
    const float* b_z    = (const float*)d_in[8];
    const float* W_cat  = (const float*)d_in[9];
    const float* b_cat  = (const float*)d_in[10];
    const float* W_beta = (const float*)d_in[11];
    const float* b_beta = (const float*)d_in[12];
    const float* W_ih   = (const float*)d_in[13];
    const float* b_ih   = (const float*)d_in[14];
    const float* W_hh   = (const float*)d_in[15];
    const float* b_hh   = (const float*)d_in[16];

    // zero hid / den / per-t loss / barrier counters (ws is poisoned 0xAA each launch)
    hipMemsetAsync(d_ws, 0, ZERO_FLOATS * sizeof(float), stream);

    mgru_main<<<NB, NT, 0, stream>>>(inp, W_dh, b_dh, w_dx, b_dx, W_out, b_out,
                                     W_z, b_z, W_cat, b_cat, W_beta, b_beta,
                                     W_ih, b_ih, W_hh, b_hh,
                                     (float*)d_out, (float*)d_ws);
}

// Round 6
// 30661.804 us; speedup vs baseline: 1.0696x; 1.0688x over previous
//
#include <hip/hip_runtime.h>
#include <cmath>

#define NB 256
#define NT 256

static constexpr int B = 1024, T = 100, F = 128, H = 512;
static constexpr size_t BTF = (size_t)B * T * F;         // 13107200
static constexpr int TF = T * F;                          // 12800
static constexpr int STRB = 4 * T * F;                    // 51200 (per-b stride in inp)

// ---- workspace layout (float/u32 offsets) ----
static constexpr size_t OFF_FLAGS = 0;                     // 256*16 u32 arrival flags (zeroed)
static constexpr size_t OFF_REL   = 4096;                  // 16 u32 release line (zeroed)
static constexpr size_t OFF_DEN   = 4112;                  // 128 (zeroed)
static constexpr size_t OFF_LOSST = 4240;                  // 128 per-t loss (zeroed)
static constexpr size_t OFF_HID   = 4368;                  // B*H (zeroed)
static constexpr size_t ZERO_FLOATS = OFF_HID + (size_t)B * H;     // 528656
static constexpr size_t OFF_H    = ZERO_FLOATS;                    // hdec B*H
static constexpr size_t OFF_GH   = OFF_H + (size_t)B * H;          // B*3H
static constexpr size_t OFF_XHAT = OFF_GH + (size_t)B * 3 * H;     // B*F
static constexpr size_t OFF_CONC = OFF_XHAT + (size_t)B * F;
static constexpr size_t OFF_BETA = OFF_CONC + (size_t)B * F;
static constexpr size_t OFF_CC   = OFF_BETA + (size_t)B * F;

__device__ __forceinline__ float4 ld4(const float* p) {
    return *reinterpret_cast<const float4*>(p);
}
__device__ __forceinline__ float sigm(float x) { return 1.f / (1.f + expf(-x)); }

// Contention-free grid barrier: per-block flag lines (plain stores, no RMW),
// block 0 gathers with 256 parallel polls, single release line polled slowly.
// Generation counter is monotone -> no resets, safe across all ~500 barriers.
__device__ __forceinline__ void gsync(unsigned* flags, unsigned* rel, unsigned gen) {
    __syncthreads();
    __threadfence();
    const int tid = threadIdx.x;
    if (blockIdx.x == 0) {
        if (tid > 0) {
            while (__hip_atomic_load(&flags[(size_t)tid * 16], __ATOMIC_RELAXED,
                                     __HIP_MEMORY_SCOPE_AGENT) < gen)
                __builtin_amdgcn_s_sleep(4);
        }
        __syncthreads();
        if (tid == 0)
            __hip_atomic_store(rel, gen, __ATOMIC_RELAXED, __HIP_MEMORY_SCOPE_AGENT);
    } else {
        if (tid == 0) {
            __hip_atomic_store(&flags[(size_t)blockIdx.x * 16], gen, __ATOMIC_RELAXED,
                               __HIP_MEMORY_SCOPE_AGENT);
            while (__hip_atomic_load(rel, __ATOMIC_RELAXED,
                                     __HIP_MEMORY_SCOPE_AGENT) < gen)
                __builtin_amdgcn_s_sleep(16);
        }
    }
    __threadfence();
    __syncthreads();
}

// write one float4 (4 consecutive k, one row) into k-major LDS tile [32][64]
__device__ __forceinline__ void stage4(float* __restrict__ dst, int k, int r, float4 p) {
    dst[(k + 0) * 64 + r] = p.x; dst[(k + 1) * 64 + r] = p.y;
    dst[(k + 2) * 64 + r] = p.z; dst[(k + 3) * 64 + r] = p.w;
}

// C_tile[64x64] = A[64xK] * B[64xK]^T ; loaders return float4 over 4 consecutive k.
// Coalesced staging (4-lane clusters read contiguous 64B), double-buffered LDS,
// next chunk prefetched into registers during compute.
template <typename FA, typename FB>
__device__ __forceinline__ void gemm_tile64(int K, FA loadA4, FB loadB4,
                                            float* __restrict__ sAB, float acc[4][4]) {
    const int tid = threadIdx.x;
    const int lr = tid >> 2;            // 0..63 : row (A) / col (B) staged by this thread
    const int lk = (tid & 3) << 2;      // 0,4,8,12 : first k of this thread's float4
    const int tx = tid & 15, ty = tid >> 4;
    const int nc = K >> 5;

    float4 pa0 = loadA4(lr, lk);
    float4 pa1 = loadA4(lr, lk + 16);
    float4 pb0 = loadB4(lr, lk);
    float4 pb1 = loadB4(lr, lk + 16);
    stage4(sAB, lk, lr, pa0);
    stage4(sAB, lk + 16, lr, pa1);
    stage4(sAB + 2048, lk, lr, pb0);
    stage4(sAB + 2048, lk + 16, lr, pb1);
    __syncthreads();

    for (int c = 0; c < nc; ++c) {
        const float* sA = sAB + (c & 1) * 4096;
        const float* sB = sA + 2048;
        if (c + 1 < nc) {
            const int k0 = (c + 1) << 5;
            pa0 = loadA4(lr, k0 + lk);
            pa1 = loadA4(lr, k0 + lk + 16);
            pb0 = loadB4(lr, k0 + lk);
            pb1 = loadB4(lr, k0 + lk + 16);
        }
#pragma unroll
        for (int kk = 0; kk < 32; ++kk) {
            const float4 av = *reinterpret_cast<const float4*>(&sA[kk * 64 + ty * 4]);
            const float4 bv = *reinterpret_cast<const float4*>(&sB[kk * 64 + tx * 4]);
            const float a0[4] = {av.x, av.y, av.z, av.w};
            const float b0[4] = {bv.x, bv.y, bv.z, bv.w};
#pragma unroll
            for (int i = 0; i < 4; ++i)
#pragma unroll
                for (int j = 0; j < 4; ++j)
                    acc[i][j] = fmaf(a0[i], b0[j], acc[i][j]);
        }
        if (c + 1 < nc) {
            float* dA = sAB + ((c + 1) & 1) * 4096;
            stage4(dA, lk, lr, pa0);
            stage4(dA, lk + 16, lr, pa1);
            stage4(dA + 2048, lk, lr, pb0);
            stage4(dA + 2048, lk + 16, lr, pb1);
        }
        __syncthreads();
    }
}

__global__ void __launch_bounds__(NT) mgru_main(
    const float* __restrict__ inp,
    const float* __restrict__ W_dh, const float* __restrict__ b_dh,
    const float* __restrict__ w_dx, const float* __restrict__ b_dx,
    const float* __restrict__ W_out, const float* __restrict__ b_out,
    const float* __restrict__ W_z,   const float* __restrict__ b_z,
    const float* __restrict__ W_cat, const float* __restrict__ b_cat,
    const float* __restrict__ W_beta,const float* __restrict__ b_beta,
    const float* __restrict__ W_ih,  const float* __restrict__ b_ih,
    const float* __restrict__ W_hh,  const float* __restrict__ b_hh,
    float* __restrict__ out, float* __restrict__ ws)
{
    __shared__ float sAB[2 * 4096];   // 32 KiB: 2 bufs x (A 32x64 + B 32x64)

    unsigned* flags = reinterpret_cast<unsigned*>(ws) + OFF_FLAGS;
    unsigned* rel   = reinterpret_cast<unsigned*>(ws) + OFF_REL;
    float* den   = ws + OFF_DEN;
    float* lossT = ws + OFF_LOSST;
    float* hid   = ws + OFF_HID;
    float* hdec  = ws + OFF_H;
    float* gh    = ws + OFF_GH;
    float* xhat  = ws + OFF_XHAT;
    float* conc  = ws + OFF_CONC;
    float* betav = ws + OFF_BETA;
    float* ccw   = ws + OFF_CC;

    const int bid = blockIdx.x, tid = threadIdx.x;
    const int tx = tid & 15, ty = tid >> 4;
    unsigned gen = 1;

    // ---- prologue: den[t] = sum_b,f masks[b,t,f] ----
    for (int s = bid * NT + tid; s < B * T; s += NB * NT) {
        int b = s / T, t = s - b * T;
        const float* mrow = inp + (size_t)b * STRB + 2 * TF + (size_t)t * F;
        float sum = 0.f;
        for (int f = 0; f < F; f += 4) {
            float4 m4 = ld4(mrow + f);
            sum += m4.x + m4.y + m4.z + m4.w;
        }
        atomicAdd(&den[t], sum);
    }
    gsync(flags, rel, gen); ++gen;

    for (int t = 0; t < T; ++t) {
        const size_t tF = (size_t)t * F;
        // ===== Phase 1: gamma_h+hdec (64..191), x_hat (192..223), beta (224..255) =====
        if (bid >= 64 && bid < 192) {      // gamma_h & hdec : [1024,512], K=128
            const int idx = bid - 64, rt = idx >> 3, ct = idx & 7;
            float acc[4][4] = {};
            gemm_tile64(128,
                [=](int r, int k) { return ld4(inp + (size_t)(rt * 64 + r) * STRB + TF + tF + k); },
                [=](int c, int k) { return ld4(W_dh + (size_t)(ct * 64 + c) * F + k); },
                sAB, acc);
#pragma unroll
            for (int i = 0; i < 4; ++i) {
                int b = rt * 64 + ty * 4 + i;
#pragma unroll
                for (int j = 0; j < 4; ++j) {
                    int c = ct * 64 + tx * 4 + j;
                    float g = expf(-fmaxf(acc[i][j] + b_dh[c], 0.f));
                    hdec[(size_t)b * H + c] = hid[(size_t)b * H + c] * g;
                }
            }
        } else if (bid >= 192 && bid < 224) {  // x_hat : [1024,128], K=512
            const int t2 = bid - 192, rt = t2 >> 1, ct = t2 & 1;
            float acc[4][4] = {};
            gemm_tile64(512,
                [=](int r, int k) { return ld4(hid + (size_t)(rt * 64 + r) * H + k); },
                [=](int c, int k) { return ld4(W_out + (size_t)(ct * 64 + c) * H + k); },
                sAB, acc);
#pragma unroll
            for (int i = 0; i < 4; ++i) {
                int b = rt * 64 + ty * 4 + i;
#pragma unroll
                for (int j = 0; j < 4; ++j) {
                    int c = ct * 64 + tx * 4 + j;
                    xhat[(size_t)b * F + c] = acc[i][j] + b_out[c];
                }
            }
        } else if (bid >= 224) {  // beta : [1024,128], K=256 (gamma_x inline in A-loader)
            const int t2 = bid - 224, rt = t2 >> 1, ct = t2 & 1;
            float acc[4][4] = {};
            gemm_tile64(256,
                [=](int r, int k) {
                    int b = rt * 64 + r;
                    if (k < 128) {
                        float4 d4 = ld4(inp + (size_t)b * STRB + TF + tF + k);
                        float4 w4 = ld4(w_dx + k), c4 = ld4(b_dx + k);
                        float4 q;
                        q.x = expf(-fmaxf(fmaf(d4.x, w4.x, c4.x), 0.f));
                        q.y = expf(-fmaxf(fmaf(d4.y, w4.y, c4.y), 0.f));
                        q.z = expf(-fmaxf(fmaf(d4.z, w4.z, c4.z), 0.f));
                        q.w = expf(-fmaxf(fmaf(d4.w, w4.w, c4.w), 0.f));
                        return q;
                    }
                    return ld4(inp + (size_t)b * STRB + 2 * TF + tF + (k - 128));
                },
                [=](int c, int k) { return ld4(W_beta + (size_t)(ct * 64 + c) * (2 * F) + k); },
                sAB, acc);
#pragma unroll
            for (int i = 0; i < 4; ++i) {
                int b = rt * 64 + ty * 4 + i;
#pragma unroll
                for (int j = 0; j < 4; ++j) {
                    int c = ct * 64 + tx * 4 + j;
                    betav[(size_t)b * F + c] = sigm(acc[i][j] + b_beta[c]);
                }
            }
        }
        gsync(flags, rel, gen); ++gen;
        // ===== Phase 2: gh (all blocks; 64..191 x2) + concat (192..223) =====
        {
            int g0 = -1, g1 = -1, cat2 = -1;
            if (bid >= 64 && bid < 192) { g0 = (bid - 64) * 2; g1 = g0 + 1; }
            else if (bid >= 192)        { g0 = 256 + (bid - 192); if (bid < 224) cat2 = bid - 192; }
            else                        { g0 = 320 + bid; }
#pragma unroll 1
            for (int pass = 0; pass < 2; ++pass) {
                int g = pass ? g1 : g0;
                if (g < 0) continue;
                const int rt = g / 24, ct = g % 24;
                float acc[4][4] = {};
                gemm_tile64(512,
                    [=](int r, int k) { return ld4(hdec + (size_t)(rt * 64 + r) * H + k); },
                    [=](int c, int k) { return ld4(W_hh + (size_t)(ct * 64 + c) * H + k); },
                    sAB, acc);
#pragma unroll
                for (int i = 0; i < 4; ++i) {
                    int b = rt * 64 + ty * 4 + i;
#pragma unroll
                    for (int j = 0; j < 4; ++j) {
                        int c = ct * 64 + tx * 4 + j;
                        gh[(size_t)b * 1536 + c] = acc[i][j] + b_hh[c];
                    }
                }
            }
            if (cat2 >= 0) {  // concat_hat : [1024,128], K=256
                const int rt = cat2 >> 1, ct = cat2 & 1;
                float acc[4][4] = {};
                gemm_tile64(256,
                    [=](int r, int k) {
                        int b = rt * 64 + r;
                        if (k < 128) {
                            float4 v4 = ld4(inp + (size_t)b * STRB + tF + k);
                            float4 m4 = ld4(inp + (size_t)b * STRB + 2 * TF + tF + k);
                            float4 x4 = ld4(xhat + (size_t)b * F + k);
                            float4 q;
                            q.x = m4.x * v4.x + (1.f - m4.x) * x4.x;
                            q.y = m4.y * v4.y + (1.f - m4.y) * x4.y;
                            q.z = m4.z * v4.z + (1.f - m4.z) * x4.z;
                            q.w = m4.w * v4.w + (1.f - m4.w) * x4.w;
                            return q;
                        }
                        return ld4(inp + (size_t)b * STRB + 3 * TF + tF + (k - 128));
                    },
                    [=](int c, int k) { return ld4(W_cat + (size_t)(ct * 64 + c) * (2 * F) + k); },
                    sAB, acc);
#pragma unroll
                for (int i = 0; i < 4; ++i) {
                    int b = rt * 64 + ty * 4 + i;
#pragma unroll
                    for (int j = 0; j < 4; ++j) {
                        int c = ct * 64 + tx * 4 + j;
                        conc[(size_t)b * F + c] = acc[i][j] + b_cat[c];
                    }
                }
            }
        }
        gsync(flags, rel, gen); ++gen;
        // ===== Phase 3: z_hat chain + outputs + loss (32..63) =====
        if (bid >= 32 && bid < 64) {
            const int t2 = bid - 32, rt = t2 >> 1, ct = t2 & 1;
            float acc[4][4] = {};
            gemm_tile64(128,
                [=](int r, int k) {
                    int b = rt * 64 + r;
                    float4 v4 = ld4(inp + (size_t)b * STRB + tF + k);
                    float4 m4 = ld4(inp + (size_t)b * STRB + 2 * TF + tF + k);
                    float4 c4 = ld4(conc + (size_t)b * F + k);
                    float4 q;
                    q.x = m4.x * v4.x + (1.f - m4.x) * c4.x;
                    q.y = m4.y * v4.y + (1.f - m4.y) * c4.y;
                    q.z = m4.z * v4.z + (1.f - m4.z) * c4.z;
                    q.w = m4.w * v4.w + (1.f - m4.w) * c4.w;
                    return q;
                },
                [=](int c, int k) {
                    float4 w = ld4(W_z + (size_t)(ct * 64 + c) * F + k);
                    int cg = ct * 64 + c;  // zero diagonal of W_z
                    w.x = (cg == k + 0) ? 0.f : w.x;
                    w.y = (cg == k + 1) ? 0.f : w.y;
                    w.z = (cg == k + 2) ? 0.f : w.z;
                    w.w = (cg == k + 3) ? 0.f : w.w;
                    return w;
                },
                sAB, acc);
            float lsum = 0.f;
#pragma unroll
            for (int i = 0; i < 4; ++i) {
                int b = rt * 64 + ty * 4 + i;
#pragma unroll
                for (int j = 0; j < 4; ++j) {
                    int c = ct * 64 + tx * 4 + j;
                    float zh = acc[i][j] + b_z[c];
                    float xh = xhat[(size_t)b * F + c];
                    float bt = betav[(size_t)b * F + c];
                    float ch = bt * zh + (1.f - bt) * xh;
                    const size_t ib = (size_t)b * STRB + tF;
                    float v = inp[ib + c];
                    float m = inp[ib + 2 * TF + c];
                    float cc = m * v + (1.f - m) * ch;
                    out[(size_t)b * TF + tF + c] = ch;
                    out[BTF + (size_t)b * TF + tF + c] = cc;
                    ccw[(size_t)b * F + c] = cc;
                    float co = conc[(size_t)b * F + c];
                    lsum += m * (2.f * fabsf(v - xh) + fabsf(v - co) +
                                 fabsf(v - zh) + fabsf(v - ch));
                }
            }
            __syncthreads();
            sAB[tid] = lsum;
            __syncthreads();
            for (int s = 128; s > 0; s >>= 1) {
                if (tid < s) sAB[tid] += sAB[tid + s];
                __syncthreads();
            }
            if (tid == 0) atomicAdd(&lossT[t], sAB[0] / (den[t] + 1e-5f));
        }
        gsync(flags, rel, gen); ++gen;
        // ===== Phase 4: gi (3 gates) + h_new (64..191) =====
        if (bid >= 64 && bid < 192) {
            const int idx = bid - 64, rt = idx >> 3, hc = idx & 7;
            float acc3[3][4][4] = {};
#pragma unroll
            for (int g = 0; g < 3; ++g) {
                gemm_tile64(256,
                    [=](int r, int k) {
                        int b = rt * 64 + r;
                        if (k < 128) return ld4(ccw + (size_t)b * F + k);
                        return ld4(inp + (size_t)b * STRB + 2 * TF + tF + (k - 128));
                    },
                    [=](int c, int k) { return ld4(W_ih + (size_t)(g * H + hc * 64 + c) * (2 * F) + k); },
                    sAB, acc3[g]);
            }
#pragma unroll
            for (int i = 0; i < 4; ++i) {
                int b = rt * 64 + ty * 4 + i;
#pragma unroll
                for (int j = 0; j < 4; ++j) {
                    int c = hc * 64 + tx * 4 + j;
                    float ir  = acc3[0][i][j] + b_ih[c];
                    float iz  = acc3[1][i][j] + b_ih[H + c];
                    float inn = acc3[2][i][j] + b_ih[2 * H + c];
                    float hr = gh[(size_t)b * 1536 + c];
                    float hz = gh[(size_t)b * 1536 + H + c];
                    float hn = gh[(size_t)b * 1536 + 2 * H + c];
                    float hv = hdec[(size_t)b * H + c];
                    float rg = sigm(ir + hr);
                    float zg = sigm(iz + hz);
                    float ng = tanhf(inn + rg * hn);
                    hid[(size_t)b * H + c] = (1.f - zg) * ng + zg * hv;
                }
            }
        }
        gsync(flags, rel, gen); ++gen;
    }
    if (bid == 0 && tid == 0) {
        float s = 0.f;
        for (int t = 0; t < T; ++t) s += lossT[t];
        out[2 * BTF] = s * 5.0f;
    }
}

extern "C" void kernel_launch(void* const* d_in, const int* in_sizes, int n_in,
                              void* d_out, int out_size, void* d_ws, size_t ws_size,
                              hipStream_t stream) {
    const float* inp    = (const float*)d_in[0];
    const float* W_dh   = (const float*)d_in[1];
    const float* b_dh   = (const float*)d_in[2];
    const float* w_dx   = (const float*)d_in[3];
    const float* b_dx   = (const float*)d_in[4];
    const float* W_out  = (const float*)d_in[5];
    const float* b_out  = (const float*)d_in[6];
    const float* W_z    = (const float*)d_in[7];
    const float* b_z    = (const float*)d_in[8];
    const float* W_cat  = (const float*)d_in[9];
    const float* b_cat  = (const float*)d_in[10];
    const float* W_beta = (const float*)d_in[11];
    const float* b_beta = (const float*)d_in[12];
    const float* W_ih   = (const float*)d_in[13];
    const float* b_ih   = (const float*)d_in[14];
    const float* W_hh   = (const float*)d_in[15];
    const float* b_hh   = (const float*)d_in[16];

    // zero flags / release / den / per-t loss / hid (ws is poisoned 0xAA each launch)
    hipMemsetAsync(d_ws, 0, ZERO_FLOATS * sizeof(float), stream);

    mgru_main<<<NB, NT, 0, stream>>>(inp, W_dh, b_dh, w_dx, b_dx, W_out, b_out,
                                     W_z, b_z, W_cat, b_cat, W_beta, b_beta,
                                     W_ih, b_ih, W_hh, b_hh,
                                     (float*)d_out, (float*)d_ws);
}